// Round 17
// baseline (134.280 us; speedup 1.0000x reference)
//
#include <hip/hip_runtime.h>

#define D 64
#define NCLS 10
#define NG 128
#define NBLK 128  // partition blocks for bucket build
#define MAXNB 512 // max coarse buckets (N/256)
#define TILES 2   // 32-node tiles per k_gpool block (64 nodes/block)
#define RSH 14    // src-range shift: ranges of 16384 rows (2 MB of table)
#define NR 8      // range slots per node

// bf16 helpers (RNE encode, cheap decode)
__device__ __forceinline__ unsigned short f2bf(float v) {
    unsigned b = __float_as_uint(v);
    b += 0x7fff + ((b >> 16) & 1);
    return (unsigned short)(b >> 16);
}
__device__ __forceinline__ float bf2f(unsigned short h) {
    return __uint_as_float(((unsigned)h) << 16);
}
// unpack 2 packed bf16 (lo|hi<<16) and add into two floats
__device__ __forceinline__ void upadd(unsigned v, float& lo, float& hi) {
    lo += __uint_as_float(v << 16);
    hi += __uint_as_float(v & 0xffff0000u);
}

// ---- h_scaled = (x @ W1) * dinv(row) -> bf16, LDS-tiled register-blocked GEMM ----
__global__ __launch_bounds__(256) void k_xw1(const float* __restrict__ x,
                      const float* __restrict__ W1, const float* __restrict__ dinv,
                      int N, ushort4* __restrict__ hs4) {
    __shared__ float wl[D * D];   // W1[k][c]
    __shared__ float xt[64 * D];  // x-tile, row-major [r][k]
    int tid = threadIdx.x;
    const float4* W4 = (const float4*)W1;
    float4* wl4 = (float4*)wl;
#pragma unroll
    for (int i = 0; i < 4; ++i) wl4[i * 256 + tid] = W4[i * 256 + tid];
    int row0 = blockIdx.x * 64;
    const float4* x4 = (const float4*)x;
    float4* xt4 = (float4*)xt;
#pragma unroll
    for (int i = 0; i < 4; ++i) {
        int flat = i * 256 + tid;
        int row = row0 + (flat >> 4);
        float4 v = make_float4(0.f, 0.f, 0.f, 0.f);
        if (row < N) v = x4[(size_t)row * 16 + (flat & 15)];
        xt4[flat] = v;
    }
    __syncthreads();
    int col4 = tid & 15;
    int rowg = tid >> 4;
    float4 acc[4];
#pragma unroll
    for (int i = 0; i < 4; ++i) acc[i] = make_float4(0.f, 0.f, 0.f, 0.f);
#pragma unroll 8
    for (int k = 0; k < D; ++k) {
        float4 wv = *(const float4*)&wl[k * D + col4 * 4];
#pragma unroll
        for (int i = 0; i < 4; ++i) {
            float xv = xt[(rowg * 4 + i) * D + k];
            acc[i].x += xv * wv.x;
            acc[i].y += xv * wv.y;
            acc[i].z += xv * wv.z;
            acc[i].w += xv * wv.w;
        }
    }
#pragma unroll
    for (int i = 0; i < 4; ++i) {
        int row = row0 + rowg * 4 + i;
        if (row >= N) continue;
        float d = dinv[row];
        ushort4 o;
        o.x = f2bf(acc[i].x * d);
        o.y = f2bf(acc[i].y * d);
        o.z = f2bf(acc[i].z * d);
        o.w = f2bf(acc[i].w * d);
        hs4[(size_t)row * 16 + col4] = o;
    }
}

// ---- bucket build pass 1: per-block histogram of dst>>8 (+ zero gsum/gcnt) ----
__global__ __launch_bounds__(256) void k_bcount(const int* __restrict__ dst, int E,
                                                int NB, int* __restrict__ blkCount,
                                                float* __restrict__ gsum,
                                                float* __restrict__ gcnt) {
    __shared__ int cnt[MAXNB];
    int tid = threadIdx.x;
    int blk = blockIdx.x;
    int gt = blk * 256 + tid;
    if (gt < NG * D) gsum[gt] = 0.f;
    if (gt < NG) gcnt[gt] = 0.f;
    for (int b = tid; b < NB; b += 256) cnt[b] = 0;
    __syncthreads();
    int ch = (E + NBLK - 1) / NBLK;
    int beg = blk * ch, end = min(beg + ch, E);
    for (int i = beg + tid; i < end; i += 256) atomicAdd(&cnt[dst[i] >> 8], 1);
    __syncthreads();
    for (int b = tid; b < NB; b += 256) blkCount[b * NBLK + blk] = cnt[b];
}

// ---- bucket build pass 2: totals -> exclusive bases, per-(bucket,block) bases ----
__global__ __launch_bounds__(512) void k_bbase(int* __restrict__ blkCount, int NB, int E,
                                               int* __restrict__ bucketBase) {
    __shared__ int sd[512];
    int tid = threadIdx.x;
    int4 c[NBLK / 4];
    int tot = 0;
    if (tid < NB) {
        const int4* p = (const int4*)&blkCount[tid * NBLK];
#pragma unroll
        for (int j = 0; j < NBLK / 4; ++j) {
            c[j] = p[j];
            tot += c[j].x + c[j].y + c[j].z + c[j].w;
        }
    }
    sd[tid] = (tid < NB) ? tot : 0;
    __syncthreads();
    for (int off = 1; off < 512; off <<= 1) {
        int tmp = (tid >= off) ? sd[tid - off] : 0;
        __syncthreads();
        sd[tid] += tmp;
        __syncthreads();
    }
    if (tid < NB) {
        int run = (tid == 0) ? 0 : sd[tid - 1];
        bucketBase[tid] = run;
        int4* p = (int4*)&blkCount[tid * NBLK];
#pragma unroll
        for (int j = 0; j < NBLK / 4; ++j) {
            int t0 = c[j].x; c[j].x = run; run += t0;
            int t1 = c[j].y; c[j].y = run; run += t1;
            int t2 = c[j].z; c[j].z = run; run += t2;
            int t3 = c[j].w; c[j].w = run; run += t3;
            p[j] = c[j];
        }
    }
    if (tid == 0) bucketBase[NB] = E;
}

// ---- bucket build pass 3: place packed (src<<8)|dstLocal grouped by bucket ----
__global__ __launch_bounds__(256) void k_bplace(const int* __restrict__ src,
                                                const int* __restrict__ dst, int E,
                                                int NB, const int* __restrict__ blkCount,
                                                int* __restrict__ e2p) {
    __shared__ int cur[MAXNB];
    int tid = threadIdx.x;
    int blk = blockIdx.x;
    for (int b = tid; b < NB; b += 256) cur[b] = blkCount[b * NBLK + blk];
    __syncthreads();
    int ch = (E + NBLK - 1) / NBLK;
    int beg = blk * ch, end = min(beg + ch, E);
    for (int i = beg + tid; i < end; i += 256) {
        int s = src[i], t = dst[i];
        int pos = atomicAdd(&cur[t >> 8], 1);
        e2p[pos] = (s << 8) | (t & 255);
    }
}

// ---- fused CSR finalize: per-(node,src-range) histogram+scan -> rowptr & dinv,
// scatter srcs grouped by (dstLocal, src>>RSH). Correctness-neutral reorder.
__global__ __launch_bounds__(256) void k_csrdeg(const int* __restrict__ e2p,
                                                const int* __restrict__ bucketBase,
                                                int N, int E,
                                                int* __restrict__ rowptr,
                                                float* __restrict__ dinv,
                                                int* __restrict__ srcs) {
    __shared__ int cnt[256 * NR];
    __shared__ int cur[256 * NR];
    __shared__ int sd[256];
    int tid = threadIdx.x;
    int node0 = blockIdx.x << 8;
    int bb = bucketBase[blockIdx.x];
    int end = bucketBase[blockIdx.x + 1];
    for (int b = tid; b < 256 * NR; b += 256) cnt[b] = 0;
    __syncthreads();
    for (int i = bb + tid; i < end; i += 256) {
        int p = e2p[i];
        int key = ((p & 255) << 3) | min((p >> 8) >> RSH, NR - 1);
        atomicAdd(&cnt[key], 1);
    }
    __syncthreads();
    int c[NR];
    int tot = 0;
#pragma unroll
    for (int r = 0; r < NR; ++r) { c[r] = cnt[tid * NR + r]; tot += c[r]; }
    sd[tid] = tot;
    __syncthreads();
    for (int off = 1; off < 256; off <<= 1) {
        int tmp = (tid >= off) ? sd[tid - off] : 0;
        __syncthreads();
        sd[tid] += tmp;
        __syncthreads();
    }
    int excl = (tid == 0) ? 0 : sd[tid - 1];
    int node = node0 + tid;
    if (node < N) {
        rowptr[node] = bb + excl;
        dinv[node] = rsqrtf((float)(tot + 1));
    }
    {
        int run = bb + excl;
#pragma unroll
        for (int r = 0; r < NR; ++r) { cur[tid * NR + r] = run; run += c[r]; }
    }
    if (blockIdx.x == 0 && tid == 0) rowptr[N] = E;
    __syncthreads();
    for (int i = bb + tid; i < end; i += 256) {
        int p = e2p[i];
        int s = p >> 8;
        int key = ((p & 255) << 3) | min(s >> RSH, NR - 1);
        int pos = atomicAdd(&cur[key], 1);
        srcs[pos] = s;
    }
}

// ---- fused gather + relu + mean-pool: 8-lane groups, 8-deep MLP, quartet reduce ----
__global__ __launch_bounds__(256) void k_gpool(
    const uint4* __restrict__ hsv, const float* __restrict__ dinv,
    const int* __restrict__ rowptr, const int* __restrict__ srcs,
    const int* __restrict__ batch, const float* __restrict__ b1, int N,
    float* __restrict__ gsum, float* __restrict__ gcnt) {
    __shared__ float lds[32 * 68];
    __shared__ int bt[32];
    int tid = threadIdx.x;
    int g32 = tid >> 3;     // group (node slot 0..31)
    int c8 = tid & 7;       // channel octet: channels c8*8 .. c8*8+7
    float4 blo = ((const float4*)b1)[c8 * 2];
    float4 bhi = ((const float4*)b1)[c8 * 2 + 1];
    int ch = tid & 63;      // channel for reduce phase
    int qg0 = (tid >> 6) * 8;  // quartet's group range [qg0, qg0+8)
    float psum = 0.f;
    float pcnt = 0.f;
    int cur_g = -1;
    int base0 = blockIdx.x * (32 * TILES);
    for (int t = 0; t < TILES; ++t) {
        int node = base0 + t * 32 + g32;
        float4 alo = make_float4(0.f, 0.f, 0.f, 0.f);
        float4 ahi = make_float4(0.f, 0.f, 0.f, 0.f);
        if (node < N) {
            int begin = rowptr[node];
            int end = rowptr[node + 1];
            {   // self-loop (already *dinv[node])
                uint4 v = hsv[(size_t)node * 8 + c8];
                upadd(v.x, alo.x, alo.y); upadd(v.y, alo.z, alo.w);
                upadd(v.z, ahi.x, ahi.y); upadd(v.w, ahi.z, ahi.w);
            }
            int k = begin;
            for (; k + 7 < end; k += 8) {  // eight independent gathers in flight
                int s0 = srcs[k],     s1 = srcs[k + 1];
                int s2 = srcs[k + 2], s3 = srcs[k + 3];
                int s4 = srcs[k + 4], s5 = srcs[k + 5];
                int s6 = srcs[k + 6], s7 = srcs[k + 7];
                uint4 v0 = hsv[(size_t)s0 * 8 + c8];
                uint4 v1 = hsv[(size_t)s1 * 8 + c8];
                uint4 v2 = hsv[(size_t)s2 * 8 + c8];
                uint4 v3 = hsv[(size_t)s3 * 8 + c8];
                uint4 v4 = hsv[(size_t)s4 * 8 + c8];
                uint4 v5 = hsv[(size_t)s5 * 8 + c8];
                uint4 v6 = hsv[(size_t)s6 * 8 + c8];
                uint4 v7 = hsv[(size_t)s7 * 8 + c8];
                upadd(v0.x, alo.x, alo.y); upadd(v0.y, alo.z, alo.w);
                upadd(v0.z, ahi.x, ahi.y); upadd(v0.w, ahi.z, ahi.w);
                upadd(v1.x, alo.x, alo.y); upadd(v1.y, alo.z, alo.w);
                upadd(v1.z, ahi.x, ahi.y); upadd(v1.w, ahi.z, ahi.w);
                upadd(v2.x, alo.x, alo.y); upadd(v2.y, alo.z, alo.w);
                upadd(v2.z, ahi.x, ahi.y); upadd(v2.w, ahi.z, ahi.w);
                upadd(v3.x, alo.x, alo.y); upadd(v3.y, alo.z, alo.w);
                upadd(v3.z, ahi.x, ahi.y); upadd(v3.w, ahi.z, ahi.w);
                upadd(v4.x, alo.x, alo.y); upadd(v4.y, alo.z, alo.w);
                upadd(v4.z, ahi.x, ahi.y); upadd(v4.w, ahi.z, ahi.w);
                upadd(v5.x, alo.x, alo.y); upadd(v5.y, alo.z, alo.w);
                upadd(v5.z, ahi.x, ahi.y); upadd(v5.w, ahi.z, ahi.w);
                upadd(v6.x, alo.x, alo.y); upadd(v6.y, alo.z, alo.w);
                upadd(v6.z, ahi.x, ahi.y); upadd(v6.w, ahi.z, ahi.w);
                upadd(v7.x, alo.x, alo.y); upadd(v7.y, alo.z, alo.w);
                upadd(v7.z, ahi.x, ahi.y); upadd(v7.w, ahi.z, ahi.w);
            }
            if (k + 3 < end) {
                int s0 = srcs[k],     s1 = srcs[k + 1];
                int s2 = srcs[k + 2], s3 = srcs[k + 3];
                uint4 v0 = hsv[(size_t)s0 * 8 + c8];
                uint4 v1 = hsv[(size_t)s1 * 8 + c8];
                uint4 v2 = hsv[(size_t)s2 * 8 + c8];
                uint4 v3 = hsv[(size_t)s3 * 8 + c8];
                upadd(v0.x, alo.x, alo.y); upadd(v0.y, alo.z, alo.w);
                upadd(v0.z, ahi.x, ahi.y); upadd(v0.w, ahi.z, ahi.w);
                upadd(v1.x, alo.x, alo.y); upadd(v1.y, alo.z, alo.w);
                upadd(v1.z, ahi.x, ahi.y); upadd(v1.w, ahi.z, ahi.w);
                upadd(v2.x, alo.x, alo.y); upadd(v2.y, alo.z, alo.w);
                upadd(v2.z, ahi.x, ahi.y); upadd(v2.w, ahi.z, ahi.w);
                upadd(v3.x, alo.x, alo.y); upadd(v3.y, alo.z, alo.w);
                upadd(v3.z, ahi.x, ahi.y); upadd(v3.w, ahi.z, ahi.w);
                k += 4;
            }
            if (k + 1 < end) {
                int s0 = srcs[k], s1 = srcs[k + 1];
                uint4 v0 = hsv[(size_t)s0 * 8 + c8];
                uint4 v1 = hsv[(size_t)s1 * 8 + c8];
                upadd(v0.x, alo.x, alo.y); upadd(v0.y, alo.z, alo.w);
                upadd(v0.z, ahi.x, ahi.y); upadd(v0.w, ahi.z, ahi.w);
                upadd(v1.x, alo.x, alo.y); upadd(v1.y, alo.z, alo.w);
                upadd(v1.z, ahi.x, ahi.y); upadd(v1.w, ahi.z, ahi.w);
                k += 2;
            }
            if (k < end) {
                int s = srcs[k];
                uint4 v = hsv[(size_t)s * 8 + c8];
                upadd(v.x, alo.x, alo.y); upadd(v.y, alo.z, alo.w);
                upadd(v.z, ahi.x, ahi.y); upadd(v.w, ahi.z, ahi.w);
            }
            float d = dinv[node];
            alo.x = fmaxf(alo.x * d + blo.x, 0.f);
            alo.y = fmaxf(alo.y * d + blo.y, 0.f);
            alo.z = fmaxf(alo.z * d + blo.z, 0.f);
            alo.w = fmaxf(alo.w * d + blo.w, 0.f);
            ahi.x = fmaxf(ahi.x * d + bhi.x, 0.f);
            ahi.y = fmaxf(ahi.y * d + bhi.y, 0.f);
            ahi.z = fmaxf(ahi.z * d + bhi.z, 0.f);
            ahi.w = fmaxf(ahi.w * d + bhi.w, 0.f);
        }
        float* row = &lds[g32 * 68 + c8 * 8];
        row[0] = alo.x; row[1] = alo.y; row[2] = alo.z; row[3] = alo.w;
        row[4] = ahi.x; row[5] = ahi.y; row[6] = ahi.z; row[7] = ahi.w;
        if (c8 == 0) bt[g32] = (node < N) ? batch[node] : -1;
        __syncthreads();
        // quartet reduce: all 4 waves active, each handles 8 groups
        for (int g = qg0; g < qg0 + 8; ++g) {
            int bg = bt[g];
            if (bg < 0) break;  // tail (invalid nodes only at the end)
            if (bg != cur_g) {
                if (cur_g >= 0) {
                    atomicAdd(&gsum[cur_g * D + ch], psum);
                    if (ch == 0) atomicAdd(&gcnt[cur_g], pcnt);
                }
                psum = 0.f; pcnt = 0.f; cur_g = bg;
            }
            psum += lds[g * 68 + ch];
            pcnt += 1.f;
        }
        __syncthreads();
    }
    if (cur_g >= 0) {
        atomicAdd(&gsum[cur_g * D + ch], psum);
        if (ch == 0) atomicAdd(&gcnt[cur_g], pcnt);
    }
}

// ---- head ----
__global__ void k_head(const float* __restrict__ gsum, const float* __restrict__ gcnt,
                       const float* __restrict__ W2, const float* __restrict__ b2,
                       float* __restrict__ out) {
    int g = threadIdx.x;
    if (g >= NG) return;
    float cnt = gcnt[g];
    cnt = cnt > 1.f ? cnt : 1.f;
    float inv = 1.f / cnt;
    float logits[NCLS];
#pragma unroll
    for (int c = 0; c < NCLS; ++c) logits[c] = b2[c];
    for (int k = 0; k < D; ++k) {
        float hk = gsum[g * D + k] * inv;
#pragma unroll
        for (int c = 0; c < NCLS; ++c) logits[c] += hk * W2[k * NCLS + c];
    }
    float m = logits[0];
#pragma unroll
    for (int c = 1; c < NCLS; ++c) m = fmaxf(m, logits[c]);
    float se = 0.f;
#pragma unroll
    for (int c = 0; c < NCLS; ++c) se += expf(logits[c] - m);
    float lse = m + logf(se);
#pragma unroll
    for (int c = 0; c < NCLS; ++c) out[g * NCLS + c] = logits[c] - lse;
}

static inline size_t pad256(size_t x) { return (x + 255) & ~(size_t)255; }

extern "C" void kernel_launch(void* const* d_in, const int* in_sizes, int n_in,
                              void* d_out, int out_size, void* d_ws, size_t ws_size,
                              hipStream_t stream) {
    const float* x     = (const float*)d_in[0];
    const int*   ei    = (const int*)d_in[1];   // [2, E]: src row then dst row
    const int*   batch = (const int*)d_in[2];
    const float* W1    = (const float*)d_in[3];
    const float* b1    = (const float*)d_in[4];
    const float* W2    = (const float*)d_in[5];
    const float* b2    = (const float*)d_in[6];
    float* out = (float*)d_out;

    const int N = in_sizes[0] / D;   // 100000
    const int E = in_sizes[1] / 2;   // 1000000
    const int NB = (N + 255) >> 8;   // 391 coarse buckets

    char* w = (char*)d_ws;
    ushort4* hs4      = (ushort4*)w; w += pad256((size_t)N * D * 2);
    float* dinv       = (float*)w;  w += pad256((size_t)N * 4);
    int*   rowptr     = (int*)w;    w += pad256((size_t)(N + 1) * 4);
    int*   srcs       = (int*)w;    w += pad256((size_t)E * 4);
    int*   e2p        = (int*)w;    w += pad256((size_t)E * 4);
    int*   blkCount   = (int*)w;    w += pad256((size_t)MAXNB * NBLK * 4);
    int*   bucketBase = (int*)w;    w += pad256((size_t)(MAXNB + 1) * 4);
    float* gsum       = (float*)w;  w += pad256((size_t)NG * D * 4);
    float* gcnt      = (float*)w;   w += pad256((size_t)NG * 4);

    const int* e_src = ei;
    const int* e_dst = ei + E;

    k_bcount<<<NBLK, 256, 0, stream>>>(e_dst, E, NB, blkCount, gsum, gcnt);
    k_bbase<<<1, 512, 0, stream>>>(blkCount, NB, E, bucketBase);
    k_bplace<<<NBLK, 256, 0, stream>>>(e_src, e_dst, E, NB, blkCount, e2p);
    k_csrdeg<<<NB, 256, 0, stream>>>(e2p, bucketBase, N, E, rowptr, dinv, srcs);

    k_xw1<<<(N + 63) / 64, 256, 0, stream>>>(x, W1, dinv, N, hs4);

    {
        int blocks = (N + 32 * TILES - 1) / (32 * TILES);
        k_gpool<<<blocks, 256, 0, stream>>>((const uint4*)hs4, dinv, rowptr, srcs,
                                            batch, b1, N, gsum, gcnt);
    }
    k_head<<<1, 128, 0, stream>>>(gsum, gcnt, W2, b2, out);
}

// Round 18
// 107.503 us; speedup vs baseline: 1.2491x; 1.2491x over previous
//
#include <hip/hip_runtime.h>

#define D 64
#define NCLS 10
#define NG 128
#define NBLK 128  // partition blocks for bucket build
#define MAXNB 512 // max coarse buckets (N/256)
#define TILES 2   // 32-node tiles per k_gpool block (64 nodes/block)
#define RSH 14    // src-range shift: ranges of 16384 rows (2 MB of table)
#define NR 8      // range slots per node

// bf16 helpers (RNE encode, cheap decode)
__device__ __forceinline__ unsigned short f2bf(float v) {
    unsigned b = __float_as_uint(v);
    b += 0x7fff + ((b >> 16) & 1);
    return (unsigned short)(b >> 16);
}
__device__ __forceinline__ float bf2f(unsigned short h) {
    return __uint_as_float(((unsigned)h) << 16);
}
// unpack 2 packed bf16 (lo|hi<<16) and add into two floats
__device__ __forceinline__ void upadd(unsigned v, float& lo, float& hi) {
    lo += __uint_as_float(v << 16);
    hi += __uint_as_float(v & 0xffff0000u);
}

// ---- h_scaled = (x @ W1) * dinv(row) -> bf16, LDS-tiled register-blocked GEMM ----
__global__ __launch_bounds__(256) void k_xw1(const float* __restrict__ x,
                      const float* __restrict__ W1, const float* __restrict__ dinv,
                      int N, ushort4* __restrict__ hs4) {
    __shared__ float wl[D * D];   // W1[k][c]
    __shared__ float xt[64 * D];  // x-tile, row-major [r][k]
    int tid = threadIdx.x;
    const float4* W4 = (const float4*)W1;
    float4* wl4 = (float4*)wl;
#pragma unroll
    for (int i = 0; i < 4; ++i) wl4[i * 256 + tid] = W4[i * 256 + tid];
    int row0 = blockIdx.x * 64;
    const float4* x4 = (const float4*)x;
    float4* xt4 = (float4*)xt;
#pragma unroll
    for (int i = 0; i < 4; ++i) {
        int flat = i * 256 + tid;
        int row = row0 + (flat >> 4);
        float4 v = make_float4(0.f, 0.f, 0.f, 0.f);
        if (row < N) v = x4[(size_t)row * 16 + (flat & 15)];
        xt4[flat] = v;
    }
    __syncthreads();
    int col4 = tid & 15;
    int rowg = tid >> 4;
    float4 acc[4];
#pragma unroll
    for (int i = 0; i < 4; ++i) acc[i] = make_float4(0.f, 0.f, 0.f, 0.f);
#pragma unroll 8
    for (int k = 0; k < D; ++k) {
        float4 wv = *(const float4*)&wl[k * D + col4 * 4];
#pragma unroll
        for (int i = 0; i < 4; ++i) {
            float xv = xt[(rowg * 4 + i) * D + k];
            acc[i].x += xv * wv.x;
            acc[i].y += xv * wv.y;
            acc[i].z += xv * wv.z;
            acc[i].w += xv * wv.w;
        }
    }
#pragma unroll
    for (int i = 0; i < 4; ++i) {
        int row = row0 + rowg * 4 + i;
        if (row >= N) continue;
        float d = dinv[row];
        ushort4 o;
        o.x = f2bf(acc[i].x * d);
        o.y = f2bf(acc[i].y * d);
        o.z = f2bf(acc[i].z * d);
        o.w = f2bf(acc[i].w * d);
        hs4[(size_t)row * 16 + col4] = o;
    }
}

// ---- bucket build pass 1: per-block histogram of dst>>8 (+ zero gsum/gcnt) ----
__global__ __launch_bounds__(256) void k_bcount(const int* __restrict__ dst, int E,
                                                int NB, int* __restrict__ blkCount,
                                                float* __restrict__ gsum,
                                                float* __restrict__ gcnt) {
    __shared__ int cnt[MAXNB];
    int tid = threadIdx.x;
    int blk = blockIdx.x;
    int gt = blk * 256 + tid;
    if (gt < NG * D) gsum[gt] = 0.f;
    if (gt < NG) gcnt[gt] = 0.f;
    for (int b = tid; b < NB; b += 256) cnt[b] = 0;
    __syncthreads();
    int ch = (E + NBLK - 1) / NBLK;
    int beg = blk * ch, end = min(beg + ch, E);
    for (int i = beg + tid; i < end; i += 256) atomicAdd(&cnt[dst[i] >> 8], 1);
    __syncthreads();
    for (int b = tid; b < NB; b += 256) blkCount[b * NBLK + blk] = cnt[b];
}

// ---- bucket build pass 2: totals -> exclusive bases, per-(bucket,block) bases ----
__global__ __launch_bounds__(512) void k_bbase(int* __restrict__ blkCount, int NB, int E,
                                               int* __restrict__ bucketBase) {
    __shared__ int sd[512];
    int tid = threadIdx.x;
    int4 c[NBLK / 4];
    int tot = 0;
    if (tid < NB) {
        const int4* p = (const int4*)&blkCount[tid * NBLK];
#pragma unroll
        for (int j = 0; j < NBLK / 4; ++j) {
            c[j] = p[j];
            tot += c[j].x + c[j].y + c[j].z + c[j].w;
        }
    }
    sd[tid] = (tid < NB) ? tot : 0;
    __syncthreads();
    for (int off = 1; off < 512; off <<= 1) {
        int tmp = (tid >= off) ? sd[tid - off] : 0;
        __syncthreads();
        sd[tid] += tmp;
        __syncthreads();
    }
    if (tid < NB) {
        int run = (tid == 0) ? 0 : sd[tid - 1];
        bucketBase[tid] = run;
        int4* p = (int4*)&blkCount[tid * NBLK];
#pragma unroll
        for (int j = 0; j < NBLK / 4; ++j) {
            int t0 = c[j].x; c[j].x = run; run += t0;
            int t1 = c[j].y; c[j].y = run; run += t1;
            int t2 = c[j].z; c[j].z = run; run += t2;
            int t3 = c[j].w; c[j].w = run; run += t3;
            p[j] = c[j];
        }
    }
    if (tid == 0) bucketBase[NB] = E;
}

// ---- bucket build pass 3: place packed (src<<8)|dstLocal grouped by bucket ----
__global__ __launch_bounds__(256) void k_bplace(const int* __restrict__ src,
                                                const int* __restrict__ dst, int E,
                                                int NB, const int* __restrict__ blkCount,
                                                int* __restrict__ e2p) {
    __shared__ int cur[MAXNB];
    int tid = threadIdx.x;
    int blk = blockIdx.x;
    for (int b = tid; b < NB; b += 256) cur[b] = blkCount[b * NBLK + blk];
    __syncthreads();
    int ch = (E + NBLK - 1) / NBLK;
    int beg = blk * ch, end = min(beg + ch, E);
    for (int i = beg + tid; i < end; i += 256) {
        int s = src[i], t = dst[i];
        int pos = atomicAdd(&cur[t >> 8], 1);
        e2p[pos] = (s << 8) | (t & 255);
    }
}

// ---- fused CSR finalize: per-(node,src-range) histogram+scan -> rowptr & dinv,
// scatter srcs grouped by (dstLocal, src>>RSH). Correctness-neutral reorder.
__global__ __launch_bounds__(256) void k_csrdeg(const int* __restrict__ e2p,
                                                const int* __restrict__ bucketBase,
                                                int N, int E,
                                                int* __restrict__ rowptr,
                                                float* __restrict__ dinv,
                                                int* __restrict__ srcs) {
    __shared__ int cnt[256 * NR];
    __shared__ int cur[256 * NR];
    __shared__ int sd[256];
    int tid = threadIdx.x;
    int node0 = blockIdx.x << 8;
    int bb = bucketBase[blockIdx.x];
    int end = bucketBase[blockIdx.x + 1];
    for (int b = tid; b < 256 * NR; b += 256) cnt[b] = 0;
    __syncthreads();
    for (int i = bb + tid; i < end; i += 256) {
        int p = e2p[i];
        int key = ((p & 255) << 3) | min((p >> 8) >> RSH, NR - 1);
        atomicAdd(&cnt[key], 1);
    }
    __syncthreads();
    int c[NR];
    int tot = 0;
#pragma unroll
    for (int r = 0; r < NR; ++r) { c[r] = cnt[tid * NR + r]; tot += c[r]; }
    sd[tid] = tot;
    __syncthreads();
    for (int off = 1; off < 256; off <<= 1) {
        int tmp = (tid >= off) ? sd[tid - off] : 0;
        __syncthreads();
        sd[tid] += tmp;
        __syncthreads();
    }
    int excl = (tid == 0) ? 0 : sd[tid - 1];
    int node = node0 + tid;
    if (node < N) {
        rowptr[node] = bb + excl;
        dinv[node] = rsqrtf((float)(tot + 1));
    }
    {
        int run = bb + excl;
#pragma unroll
        for (int r = 0; r < NR; ++r) { cur[tid * NR + r] = run; run += c[r]; }
    }
    if (blockIdx.x == 0 && tid == 0) rowptr[N] = E;
    __syncthreads();
    for (int i = bb + tid; i < end; i += 256) {
        int p = e2p[i];
        int s = p >> 8;
        int key = ((p & 255) << 3) | min(s >> RSH, NR - 1);
        int pos = atomicAdd(&cur[key], 1);
        srcs[pos] = s;
    }
}

// ---- fused gather + relu + mean-pool, 8-lane groups (16B/lane loads) ----
// Block: 32 groups x 8 lanes, TILES tiles of 32 nodes (64 nodes/block). Per tile:
// per-group gather (4-deep MLP, uint4 loads = 8 bf16 channels/lane) -> fp32 row
// to LDS -> sync -> threads 0..63 run-accumulate over 32 rows with sorted-batch
// boundary flush (~110k flush atomics total).
// NOTE (r17 lesson): 8-deep MLP raises VGPR 40->52, occupancy 65->30% -> -23%.
// 4-deep at full occupancy is the sweet spot; do not deepen again.
__global__ __launch_bounds__(256) void k_gpool(
    const uint4* __restrict__ hsv, const float* __restrict__ dinv,
    const int* __restrict__ rowptr, const int* __restrict__ srcs,
    const int* __restrict__ batch, const float* __restrict__ b1, int N,
    float* __restrict__ gsum, float* __restrict__ gcnt) {
    __shared__ float lds[32 * 68];
    __shared__ int bt[32];
    int tid = threadIdx.x;
    int g32 = tid >> 3;     // group (node slot 0..31)
    int c8 = tid & 7;       // channel octet: channels c8*8 .. c8*8+7
    float4 blo = ((const float4*)b1)[c8 * 2];
    float4 bhi = ((const float4*)b1)[c8 * 2 + 1];
    int ch = tid;           // channel for reduce phase (threads 0..63)
    float psum = 0.f;
    float pcnt = 0.f;
    int cur_g = -1;
    int base0 = blockIdx.x * (32 * TILES);
    for (int t = 0; t < TILES; ++t) {
        int node = base0 + t * 32 + g32;
        float4 alo = make_float4(0.f, 0.f, 0.f, 0.f);
        float4 ahi = make_float4(0.f, 0.f, 0.f, 0.f);
        if (node < N) {
            int begin = rowptr[node];
            int end = rowptr[node + 1];
            {   // self-loop (already *dinv[node])
                uint4 v = hsv[(size_t)node * 8 + c8];
                upadd(v.x, alo.x, alo.y); upadd(v.y, alo.z, alo.w);
                upadd(v.z, ahi.x, ahi.y); upadd(v.w, ahi.z, ahi.w);
            }
            int k = begin;
            for (; k + 3 < end; k += 4) {  // four independent gathers in flight
                int s0 = srcs[k];
                int s1 = srcs[k + 1];
                int s2 = srcs[k + 2];
                int s3 = srcs[k + 3];
                uint4 v0 = hsv[(size_t)s0 * 8 + c8];
                uint4 v1 = hsv[(size_t)s1 * 8 + c8];
                uint4 v2 = hsv[(size_t)s2 * 8 + c8];
                uint4 v3 = hsv[(size_t)s3 * 8 + c8];
                upadd(v0.x, alo.x, alo.y); upadd(v0.y, alo.z, alo.w);
                upadd(v0.z, ahi.x, ahi.y); upadd(v0.w, ahi.z, ahi.w);
                upadd(v1.x, alo.x, alo.y); upadd(v1.y, alo.z, alo.w);
                upadd(v1.z, ahi.x, ahi.y); upadd(v1.w, ahi.z, ahi.w);
                upadd(v2.x, alo.x, alo.y); upadd(v2.y, alo.z, alo.w);
                upadd(v2.z, ahi.x, ahi.y); upadd(v2.w, ahi.z, ahi.w);
                upadd(v3.x, alo.x, alo.y); upadd(v3.y, alo.z, alo.w);
                upadd(v3.z, ahi.x, ahi.y); upadd(v3.w, ahi.z, ahi.w);
            }
            for (; k < end; ++k) {
                int s = srcs[k];
                uint4 v = hsv[(size_t)s * 8 + c8];
                upadd(v.x, alo.x, alo.y); upadd(v.y, alo.z, alo.w);
                upadd(v.z, ahi.x, ahi.y); upadd(v.w, ahi.z, ahi.w);
            }
            float d = dinv[node];
            alo.x = fmaxf(alo.x * d + blo.x, 0.f);
            alo.y = fmaxf(alo.y * d + blo.y, 0.f);
            alo.z = fmaxf(alo.z * d + blo.z, 0.f);
            alo.w = fmaxf(alo.w * d + blo.w, 0.f);
            ahi.x = fmaxf(ahi.x * d + bhi.x, 0.f);
            ahi.y = fmaxf(ahi.y * d + bhi.y, 0.f);
            ahi.z = fmaxf(ahi.z * d + bhi.z, 0.f);
            ahi.w = fmaxf(ahi.w * d + bhi.w, 0.f);
        }
        float* row = &lds[g32 * 68 + c8 * 8];
        row[0] = alo.x; row[1] = alo.y; row[2] = alo.z; row[3] = alo.w;
        row[4] = ahi.x; row[5] = ahi.y; row[6] = ahi.z; row[7] = ahi.w;
        if (c8 == 0) bt[g32] = (node < N) ? batch[node] : -1;
        __syncthreads();
        if (tid < 64) {
            for (int g = 0; g < 32; ++g) {
                int bg = bt[g];
                if (bg < 0) break;  // tail (invalid nodes only at the end)
                if (bg != cur_g) {
                    if (cur_g >= 0) {
                        atomicAdd(&gsum[cur_g * D + ch], psum);
                        if (ch == 0) atomicAdd(&gcnt[cur_g], pcnt);
                    }
                    psum = 0.f; pcnt = 0.f; cur_g = bg;
                }
                psum += lds[g * 68 + ch];
                pcnt += 1.f;
            }
        }
        __syncthreads();
    }
    if (tid < 64 && cur_g >= 0) {
        atomicAdd(&gsum[cur_g * D + ch], psum);
        if (ch == 0) atomicAdd(&gcnt[cur_g], pcnt);
    }
}

// ---- head ----
__global__ void k_head(const float* __restrict__ gsum, const float* __restrict__ gcnt,
                       const float* __restrict__ W2, const float* __restrict__ b2,
                       float* __restrict__ out) {
    int g = threadIdx.x;
    if (g >= NG) return;
    float cnt = gcnt[g];
    cnt = cnt > 1.f ? cnt : 1.f;
    float inv = 1.f / cnt;
    float logits[NCLS];
#pragma unroll
    for (int c = 0; c < NCLS; ++c) logits[c] = b2[c];
    for (int k = 0; k < D; ++k) {
        float hk = gsum[g * D + k] * inv;
#pragma unroll
        for (int c = 0; c < NCLS; ++c) logits[c] += hk * W2[k * NCLS + c];
    }
    float m = logits[0];
#pragma unroll
    for (int c = 1; c < NCLS; ++c) m = fmaxf(m, logits[c]);
    float se = 0.f;
#pragma unroll
    for (int c = 0; c < NCLS; ++c) se += expf(logits[c] - m);
    float lse = m + logf(se);
#pragma unroll
    for (int c = 0; c < NCLS; ++c) out[g * NCLS + c] = logits[c] - lse;
}

static inline size_t pad256(size_t x) { return (x + 255) & ~(size_t)255; }

extern "C" void kernel_launch(void* const* d_in, const int* in_sizes, int n_in,
                              void* d_out, int out_size, void* d_ws, size_t ws_size,
                              hipStream_t stream) {
    const float* x     = (const float*)d_in[0];
    const int*   ei    = (const int*)d_in[1];   // [2, E]: src row then dst row
    const int*   batch = (const int*)d_in[2];
    const float* W1    = (const float*)d_in[3];
    const float* b1    = (const float*)d_in[4];
    const float* W2    = (const float*)d_in[5];
    const float* b2    = (const float*)d_in[6];
    float* out = (float*)d_out;

    const int N = in_sizes[0] / D;   // 100000
    const int E = in_sizes[1] / 2;   // 1000000
    const int NB = (N + 255) >> 8;   // 391 coarse buckets

    char* w = (char*)d_ws;
    ushort4* hs4      = (ushort4*)w; w += pad256((size_t)N * D * 2);
    float* dinv       = (float*)w;  w += pad256((size_t)N * 4);
    int*   rowptr     = (int*)w;    w += pad256((size_t)(N + 1) * 4);
    int*   srcs       = (int*)w;    w += pad256((size_t)E * 4);
    int*   e2p        = (int*)w;    w += pad256((size_t)E * 4);
    int*   blkCount   = (int*)w;    w += pad256((size_t)MAXNB * NBLK * 4);
    int*   bucketBase = (int*)w;    w += pad256((size_t)(MAXNB + 1) * 4);
    float* gsum       = (float*)w;  w += pad256((size_t)NG * D * 4);
    float* gcnt      = (float*)w;   w += pad256((size_t)NG * 4);

    const int* e_src = ei;
    const int* e_dst = ei + E;

    k_bcount<<<NBLK, 256, 0, stream>>>(e_dst, E, NB, blkCount, gsum, gcnt);
    k_bbase<<<1, 512, 0, stream>>>(blkCount, NB, E, bucketBase);
    k_bplace<<<NBLK, 256, 0, stream>>>(e_src, e_dst, E, NB, blkCount, e2p);
    k_csrdeg<<<NB, 256, 0, stream>>>(e2p, bucketBase, N, E, rowptr, dinv, srcs);

    k_xw1<<<(N + 63) / 64, 256, 0, stream>>>(x, W1, dinv, N, hs4);

    {
        int blocks = (N + 32 * TILES - 1) / (32 * TILES);
        k_gpool<<<blocks, 256, 0, stream>>>((const uint4*)hs4, dinv, rowptr, srcs,
                                            batch, b1, N, gsum, gcnt);
    }
    k_head<<<1, 128, 0, stream>>>(gsum, gcnt, W2, b2, out);
}